// Round 5
// baseline (1371.466 us; speedup 1.0000x reference)
//
#include <hip/hip_runtime.h>

typedef _Float16 v8h  __attribute__((ext_vector_type(8)));
typedef _Float16 v4h  __attribute__((ext_vector_type(4)));
typedef float    v4f  __attribute__((ext_vector_type(4)));
typedef unsigned int u32x4 __attribute__((ext_vector_type(4)));

#define BATCH   128
#define TSTEPS  256
#define DFEAT   256
#define UDIM    1024
#define NCOL    2048
#define ASTRIDE 1288   // LDS A stride (halfs)

// ---------------- tagged-packet exchange geometry ----------------
// Producer (g,cb) publishes its 16x32 fp16 h-tile as 86 16-byte packets:
//   packet p = u16 slots [tag, h(6p), h(6p+1), h(6p+2), tag, h(6p+3), h(6p+4), h(6p+5)]
//   (tag per 8B half -> 64-bit tearing detected; packet 85 carries 2 valid h)
// tag value = t+1 (step being published). Parity buffers by (t+1)&1; stale slot
// holds tag t-1, overwrite only at t+3 (structurally after consumption) -> safe.
#define NPKT    86
#define PKT_DW  4
#define PROD_DW (NPKT * PKT_DW)            // 344 dwords per producer
#define PAR_DW  (8 * 32 * PROD_DW)         // 88064 dwords per parity (352,256 B)
#define PKT_BYTES (2u * 352256u)           // 704,512 B total
#define TOTPKT  (32 * NPKT)                // 2752 packets per consumer block

__global__ __launch_bounds__(1024)
void ltc_rnn_kernel(const float* __restrict__ features,  // [128,256,256]
                    const float* __restrict__ tsteps,    // [128,256]
                    const float* __restrict__ Wx,        // [256,2048]
                    const float* __restrict__ Wh,        // [1024,2048]
                    const float* __restrict__ bias,      // [2048]
                    const float* __restrict__ wtau,      // [1024]
                    const float* __restrict__ h0,        // [128,1024]
                    float* __restrict__ out,             // [128,256,1024]
                    unsigned* __restrict__ pkt)          // tagged packet buffers
{
  __shared__ _Float16 Alds[16 * ASTRIDE];
  __shared__ float    Plds[16 * 64 * 4];
  __shared__ _Float16 HoutL[528];          // 16*32 halfs (+pad for packer over-read)
  __shared__ float    dtlds[2][16];
  __shared__ unsigned hsc;                 // EW->packer handshake counter

  const int tid  = threadIdx.x;
  const int w    = tid >> 6;
  const int lane = tid & 63;
  const int n    = lane & 15;
  const int q    = lane >> 4;
  const int cg   = w & 3;
  const int ks   = w >> 2;
  const int g    = blockIdx.x & 7;
  const int cb   = blockIdx.x >> 3;
  const int u0   = cb * 32;

  if (tid == 0) hsc = 0u;

  // ---- wave-stationary weights: fp32 -> fp16 VGPRs, once ----
  const int gcol = (n < 8) ? (u0 + cg * 8 + n) : (UDIM + u0 + cg * 8 + (n - 8));
  v8h bfr[10];
  #pragma unroll
  for (int c = 0; c < 10; ++c) {
    #pragma unroll
    for (int j = 0; j < 8; ++j) {
      const int k = ks * 320 + c * 32 + q * 8 + j;
      const float wv = (k < DFEAT) ? Wx[(size_t)k * NCOL + gcol]
                                   : Wh[(size_t)(k - DFEAT) * NCOL + gcol];
      bfr[c][j] = (_Float16)wv;
    }
  }

  const float bias_own = bias[gcol];
  const int   u_lane   = u0 + cg * 8 + (n & 7);
  const float tau      = logf(1.0f + __expf(wtau[u_lane]));

  float h_reg[4];
  #pragma unroll
  for (int i = 0; i < 4; ++i)
    h_reg[i] = h0[(size_t)(g * 16 + q * 4 + i) * UDIM + u_lane];

  // ---- consumer packet-slot precompute (per thread, 3 slots; slot k -> packet tid+1024k) ----
  int cPA[3], cPB[3], cJS[3], cNV[3];
  const unsigned* cSRC[3];
  bool cFAST[3];
  #pragma unroll
  for (int k = 0; k < 3; ++k) {
    const int pi  = tid + k * 1024;
    const bool act = pi < TOTPKT;
    const int pic = act ? pi : tid;
    const int cbp = pic / NPKT;
    const int p   = pic - cbp * NPKT;
    cNV[k]  = act ? ((p == 85) ? 2 : 6) : 0;
    const int idx0 = p * 6, r0 = idx0 >> 5, c0 = idx0 & 31;
    cJS[k]  = 32 - c0;
    cPA[k]  = r0 * ASTRIDE + DFEAT + cbp * 32 + c0;
    cPB[k]  = (r0 + 1) * ASTRIDE + DFEAT + cbp * 32;
    cFAST[k] = act && (cNV[k] == 6) && (c0 <= 26);
    cSRC[k] = pkt + (size_t)(g * 32 + cbp) * PROD_DW + (size_t)p * PKT_DW;
  }
  // producer slot (waves 4,5 -> packet pp)
  const int pp = (w - 4) * 64 + lane;
  unsigned* pDST = pkt + (size_t)(g * 32 + cb) * PROD_DW + (size_t)(pp < NPKT ? pp : 0) * PKT_DW;

  // ---- pre-loop staging: x(0), dt(0), h0 ----
  if (tid < 16) dtlds[0][tid] = tsteps[(size_t)(g * 16 + tid) * TSTEPS + 0];
  {
    const int r = tid >> 6, k4 = tid & 63;
    v4f x4 = *(const v4f*)(features + (size_t)(g * 16 + r) * (TSTEPS * DFEAT) + k4 * 4);
    v4h xh = {(_Float16)x4.x, (_Float16)x4.y, (_Float16)x4.z, (_Float16)x4.w};
    *(v4h*)&Alds[r * ASTRIDE + k4 * 4] = xh;
    #pragma unroll
    for (int jj = 0; jj < 4; ++jj) {
      const int c = tid + jj * 1024, hr = c >> 8, hk4 = c & 255;
      v4f h4 = *(const v4f*)(h0 + (size_t)(g * 16 + hr) * UDIM + hk4 * 4);
      v4h hh = {(_Float16)h4.x, (_Float16)h4.y, (_Float16)h4.z, (_Float16)h4.w};
      *(v4h*)&Alds[hr * ASTRIDE + DFEAT + hk4 * 4] = hh;
    }
  }
  __syncthreads();

  for (int t = 0; t < TSTEPS; ++t) {
    const bool more = (t + 1 < TSTEPS);
    const unsigned tg = (unsigned)(t + 1);
    const size_t paroff = ((t + 1) & 1) ? (size_t)PAR_DW : 0;

    // ---- MFMA: 16 rows x 16 cols x K-slice 320, dual accumulator chains ----
    {
      v4f acc0 = {0.f, 0.f, 0.f, 0.f};
      v4f acc1 = {0.f, 0.f, 0.f, 0.f};
      const _Float16* abase = &Alds[n * ASTRIDE + ks * 320 + q * 8];
      #pragma unroll
      for (int c = 0; c < 10; c += 2) {
        v8h a0 = *(const v8h*)(abase + c * 32);
        v8h a1 = *(const v8h*)(abase + (c + 1) * 32);
        acc0 = __builtin_amdgcn_mfma_f32_16x16x32_f16(a0, bfr[c],     acc0, 0, 0, 0);
        acc1 = __builtin_amdgcn_mfma_f32_16x16x32_f16(a1, bfr[c + 1], acc1, 0, 0, 0);
      }
      v4f acc = acc0 + acc1;
      *(v4f*)&Plds[(w * 64 + lane) * 4] = acc;
    }
    __syncthreads();                                   // S1: Plds ready

    // ---- reduce + elementwise (waves 0..3); release-add for packers ----
    float outv[4];
    if (w < 4) {
      v4f p = *(v4f*)&Plds[((0 * 4 + w) * 64 + lane) * 4];
      #pragma unroll
      for (int s = 1; s < 4; ++s) {
        v4f ps = *(v4f*)&Plds[((s * 4 + w) * 64 + lane) * 4];
        p.x += ps.x; p.y += ps.y; p.z += ps.z; p.w += ps.w;
      }
      float pf[4], pa[4];
      #pragma unroll
      for (int i = 0; i < 4; ++i) {
        const float v = p[i] + bias_own;
        const float o = __shfl_xor(v, 8);
        pf[i] = v; pa[i] = o;
      }
      if (n < 8) {
        #pragma unroll
        for (int i = 0; i < 4; ++i) {
          const int   row_l = q * 4 + i;
          const float dt    = dtlds[t & 1][row_l];
          const float f     = 1.0f / (1.0f + __expf(-pf[i]));
          const float av    = 2.0f / (1.0f + __expf(-2.0f * pa[i])) - 1.0f;
          const float decay = __expf(-dt * (tau + f));
          const float hn    = (h_reg[i] - av) * decay + av;
          h_reg[i] = hn;
          outv[i]  = hn;
          HoutL[row_l * 32 + w * 8 + n] = (_Float16)hn;
        }
      }
      if (lane == 0)
        __hip_atomic_fetch_add(&hsc, 1u, __ATOMIC_RELEASE, __HIP_MEMORY_SCOPE_WORKGROUP);
    }

    // ---- off-critical-path: out stores (fire and forget) ----
    if (w < 4 && n < 8) {
      #pragma unroll
      for (int i = 0; i < 4; ++i) {
        const int row = g * 16 + q * 4 + i;
        out[(size_t)row * (TSTEPS * UDIM) + (size_t)t * UDIM + u_lane] = outv[i];
      }
    }

    // ---- x(t+1)/dt(t+1) prefetch (all waves share; drains during spins) ----
    if (more) {
      if (tid < 16) dtlds[(t + 1) & 1][tid] = tsteps[(size_t)(g * 16 + tid) * TSTEPS + t + 1];
      const int r = tid >> 6, k4 = tid & 63;
      v4f x4 = *(const v4f*)(features + (size_t)(g * 16 + r) * (TSTEPS * DFEAT)
                             + (size_t)(t + 1) * DFEAT + k4 * 4);
      v4h xh = {(_Float16)x4.x, (_Float16)x4.y, (_Float16)x4.z, (_Float16)x4.w};
      *(v4h*)&Alds[r * ASTRIDE + k4 * 4] = xh;
    }

    // ---- packers (waves 4,5): wait EW, pack Hout -> single tagged 16B store ----
    if (more && (w == 4 || w == 5)) {
      const unsigned target = 4u * (unsigned)(t + 1);
      while (__hip_atomic_load(&hsc, __ATOMIC_ACQUIRE, __HIP_MEMORY_SCOPE_WORKGROUP) < target) {}
      if (pp < NPKT) {
        const unsigned* Hw = (const unsigned*)HoutL;
        const unsigned s0 = Hw[3 * pp], s1 = Hw[3 * pp + 1], s2 = Hw[3 * pp + 2];
        u32x4 pk;
        pk.x = tg | (s0 << 16);
        pk.y = (s0 >> 16) | (s1 << 16);
        pk.z = tg | (s1 & 0xffff0000u);
        pk.w = s2;
        unsigned* dst = pDST + paroff;
        asm volatile("global_store_dwordx4 %0, %1, off sc0 sc1"
                     :: "v"(dst), "v"(pk) : "memory");
      }
    }

    // ---- consumer: poll own packets (tag==t+1 in both halves) and stage into Alds ----
    if (more) {
      const unsigned* s0p = cSRC[0] + paroff;
      const unsigned* s1p = cSRC[1] + paroff;
      const unsigned* s2p = cSRC[2] + paroff;
      bool d0 = (cNV[0] == 0), d1 = (cNV[1] == 0), d2 = (cNV[2] == 0);
      u32x4 ra, rb, rc;

#define EXTRACT_H(R, J) ((J) == 0 ? ((R).x >> 16) : (J) == 1 ? ((R).y & 0xffffu) : \
                         (J) == 2 ? ((R).y >> 16) : (J) == 3 ? ((R).z >> 16) : \
                         (J) == 4 ? ((R).w & 0xffffu) : ((R).w >> 16))
#define DEPOSIT(K, R)                                                              \
      do {                                                                         \
        if (cFAST[K]) {                                                            \
          unsigned short* b = (unsigned short*)Alds + cPA[K];                      \
          *(unsigned*)(b)     = ((R).x >> 16) | ((R).y << 16);                     \
          *(unsigned*)(b + 2) = ((R).y >> 16) | ((R).z & 0xffff0000u);             \
          *(unsigned*)(b + 4) = (R).w;                                             \
        } else {                                                                   \
          _Pragma("unroll")                                                        \
          for (int j = 0; j < 6; ++j) {                                            \
            if (j < cNV[K]) {                                                      \
              const unsigned hv = EXTRACT_H(R, j);                                 \
              const int a = (j < cJS[K]) ? (cPA[K] + j) : (cPB[K] + (j - cJS[K])); \
              ((unsigned short*)Alds)[a] = (unsigned short)hv;                     \
            }                                                                      \
          }                                                                        \
        }                                                                          \
      } while (0)

      for (;;) {
        asm volatile("global_load_dwordx4 %0, %3, off sc0 sc1\n\t"
                     "global_load_dwordx4 %1, %4, off sc0 sc1\n\t"
                     "global_load_dwordx4 %2, %5, off sc0 sc1\n\t"
                     "s_waitcnt vmcnt(0)"
                     : "=&v"(ra), "=&v"(rb), "=&v"(rc)
                     : "v"(s0p), "v"(s1p), "v"(s2p) : "memory");
        if (!d0 && ((ra.x & 0xffffu) == tg) && ((ra.z & 0xffffu) == tg)) { DEPOSIT(0, ra); d0 = true; }
        if (!d1 && ((rb.x & 0xffffu) == tg) && ((rb.z & 0xffffu) == tg)) { DEPOSIT(1, rb); d1 = true; }
        if (!d2 && ((rc.x & 0xffffu) == tg) && ((rc.z & 0xffffu) == tg)) { DEPOSIT(2, rc); d2 = true; }
        if (d0 && d1 && d2) break;
      }
#undef DEPOSIT
#undef EXTRACT_H
      __syncthreads();                                 // S4: A(t+1) ready
    }
  }
}

// ================= proven fallback (R4 kernel, flags+hbuf protocol) =================
__global__ __launch_bounds__(1024)
void ltc_rnn_fallback(const float* __restrict__ features, const float* __restrict__ tsteps,
                      const float* __restrict__ Wx, const float* __restrict__ Wh,
                      const float* __restrict__ bias, const float* __restrict__ wtau,
                      const float* __restrict__ h0, float* __restrict__ out,
                      unsigned* __restrict__ flags, _Float16* __restrict__ hbufs)
{
  __shared__ _Float16 Alds[16 * ASTRIDE];
  __shared__ float    Plds[16 * 64 * 4];
  __shared__ _Float16 Hout[16][32];
  __shared__ float    dtlds[2][16];

  const int tid  = threadIdx.x;
  const int w    = tid >> 6;
  const int lane = tid & 63;
  const int n    = lane & 15;
  const int q    = lane >> 4;
  const int cg   = w & 3;
  const int ks   = w >> 2;
  const int g    = blockIdx.x & 7;
  const int cb   = blockIdx.x >> 3;
  const int u0   = cb * 32;

  const int gcol = (n < 8) ? (u0 + cg * 8 + n) : (UDIM + u0 + cg * 8 + (n - 8));
  v8h bfr[10];
  #pragma unroll
  for (int c = 0; c < 10; ++c) {
    #pragma unroll
    for (int j = 0; j < 8; ++j) {
      const int k = ks * 320 + c * 32 + q * 8 + j;
      const float wv = (k < DFEAT) ? Wx[(size_t)k * NCOL + gcol]
                                   : Wh[(size_t)(k - DFEAT) * NCOL + gcol];
      bfr[c][j] = (_Float16)wv;
    }
  }
  const float bias_own = bias[gcol];
  const int   u_lane   = u0 + cg * 8 + (n & 7);
  const float tau      = logf(1.0f + __expf(wtau[u_lane]));
  float h_reg[4];
  #pragma unroll
  for (int i = 0; i < 4; ++i)
    h_reg[i] = h0[(size_t)(g * 16 + q * 4 + i) * UDIM + u_lane];

  if (tid < 16) dtlds[0][tid] = tsteps[(size_t)(g * 16 + tid) * TSTEPS + 0];
  {
    const int r = tid >> 6, k4 = tid & 63;
    v4f x4 = *(const v4f*)(features + (size_t)(g * 16 + r) * (TSTEPS * DFEAT) + k4 * 4);
    v4h xh = {(_Float16)x4.x, (_Float16)x4.y, (_Float16)x4.z, (_Float16)x4.w};
    *(v4h*)&Alds[r * ASTRIDE + k4 * 4] = xh;
    #pragma unroll
    for (int jj = 0; jj < 4; ++jj) {
      const int c = tid + jj * 1024, hr = c >> 8, hk4 = c & 255;
      v4f h4 = *(const v4f*)(h0 + (size_t)(g * 16 + hr) * UDIM + hk4 * 4);
      v4h hh = {(_Float16)h4.x, (_Float16)h4.y, (_Float16)h4.z, (_Float16)h4.w};
      *(v4h*)&Alds[hr * ASTRIDE + DFEAT + hk4 * 4] = hh;
    }
  }
  __syncthreads();

  for (int t = 0; t < TSTEPS; ++t) {
    const bool more = (t + 1 < TSTEPS);
    _Float16* hdst = hbufs + ((t + 1) & 1) * (BATCH * UDIM);
    {
      v4f acc0 = {0.f, 0.f, 0.f, 0.f};
      v4f acc1 = {0.f, 0.f, 0.f, 0.f};
      const _Float16* abase = &Alds[n * ASTRIDE + ks * 320 + q * 8];
      #pragma unroll
      for (int c = 0; c < 10; c += 2) {
        v8h a0 = *(const v8h*)(abase + c * 32);
        v8h a1 = *(const v8h*)(abase + (c + 1) * 32);
        acc0 = __builtin_amdgcn_mfma_f32_16x16x32_f16(a0, bfr[c],     acc0, 0, 0, 0);
        acc1 = __builtin_amdgcn_mfma_f32_16x16x32_f16(a1, bfr[c + 1], acc1, 0, 0, 0);
      }
      v4f acc = acc0 + acc1;
      *(v4f*)&Plds[(w * 64 + lane) * 4] = acc;
    }
    __syncthreads();
    float outv[4];
    if (w < 4) {
      v4f p = *(v4f*)&Plds[((0 * 4 + w) * 64 + lane) * 4];
      #pragma unroll
      for (int s = 1; s < 4; ++s) {
        v4f ps = *(v4f*)&Plds[((s * 4 + w) * 64 + lane) * 4];
        p.x += ps.x; p.y += ps.y; p.z += ps.z; p.w += ps.w;
      }
      float pf[4], pa[4];
      #pragma unroll
      for (int i = 0; i < 4; ++i) {
        const float v = p[i] + bias_own;
        const float o = __shfl_xor(v, 8);
        pf[i] = v; pa[i] = o;
      }
      if (n < 8) {
        #pragma unroll
        for (int i = 0; i < 4; ++i) {
          const int   row_l = q * 4 + i;
          const float dt    = dtlds[t & 1][row_l];
          const float f     = 1.0f / (1.0f + __expf(-pf[i]));
          const float av    = 2.0f / (1.0f + __expf(-2.0f * pa[i])) - 1.0f;
          const float decay = __expf(-dt * (tau + f));
          const float hn    = (h_reg[i] - av) * decay + av;
          h_reg[i] = hn; outv[i] = hn;
          Hout[row_l][w * 8 + n] = (_Float16)hn;
        }
      }
    }
    __syncthreads();
    if (w == 0 && more) {
      const int row = lane >> 2, c8 = lane & 3;
      v8h hv = *(v8h*)&Hout[row][c8 * 8];
      _Float16* dp = hdst + (size_t)(g * 16 + row) * UDIM + u0 + c8 * 8;
      asm volatile("global_store_dwordx4 %0, %1, off sc0 sc1\n\t"
                   "s_waitcnt vmcnt(0)"
                   :: "v"(dp), "v"(__builtin_bit_cast(u32x4, hv)) : "memory");
      if (lane == 0) {
        unsigned tgv = (unsigned)(t + 1);
        asm volatile("global_store_dword %0, %1, off sc0 sc1"
                     :: "v"(&flags[g * 64 + cb]), "v"(tgv) : "memory");
      }
    }
    const unsigned* fp = &flags[g * 64 + (lane & 31)];
    unsigned v0 = 0;
    if (more) {
      asm volatile("global_load_dword %0, %1, off sc0 sc1"
                   : "=v"(v0) : "v"(fp) : "memory");
    }
    if (w < 4 && n < 8) {
      #pragma unroll
      for (int i = 0; i < 4; ++i) {
        const int row = g * 16 + q * 4 + i;
        out[(size_t)row * (TSTEPS * UDIM) + (size_t)t * UDIM + u_lane] = outv[i];
      }
    }
    if (more) {
      if (tid < 16) dtlds[(t + 1) & 1][tid] = tsteps[(size_t)(g * 16 + tid) * TSTEPS + t + 1];
      const int r = tid >> 6, k4 = tid & 63;
      v4f x4 = *(const v4f*)(features + (size_t)(g * 16 + r) * (TSTEPS * DFEAT)
                             + (size_t)(t + 1) * DFEAT + k4 * 4);
      v4h xh = {(_Float16)x4.x, (_Float16)x4.y, (_Float16)x4.z, (_Float16)x4.w};
      *(v4h*)&Alds[r * ASTRIDE + k4 * 4] = xh;
    }
    if (more) {
      const unsigned tgc = (unsigned)t;
      asm volatile("s_waitcnt vmcnt(0)" : "+v"(v0) :: "memory");
      if (__ballot(v0 <= tgc) != 0ull) {
        for (;;) {
          unsigned v;
          asm volatile("global_load_dword %0, %1, off sc0 sc1\n\t"
                       "s_waitcnt vmcnt(0)"
                       : "=v"(v) : "v"(fp) : "memory");
          if (__ballot(v <= tgc) == 0ull) break;
        }
      }
      const _Float16* hsrc = hbufs + ((t + 1) & 1) * (BATCH * UDIM);
      const int c0 = tid, c1 = tid + 1024;
      const _Float16* p0 = hsrc + (size_t)(g * 16 + (c0 >> 7)) * UDIM + (c0 & 127) * 8;
      const _Float16* p1 = hsrc + (size_t)(g * 16 + (c1 >> 7)) * UDIM + (c1 & 127) * 8;
      u32x4 r0, r1;
      asm volatile("global_load_dwordx4 %0, %2, off sc0 sc1\n\t"
                   "global_load_dwordx4 %1, %3, off sc0 sc1\n\t"
                   "s_waitcnt vmcnt(0)"
                   : "=v"(r0), "=v"(r1) : "v"(p0), "v"(p1) : "memory");
      *(v8h*)&Alds[(c0 >> 7) * ASTRIDE + DFEAT + (c0 & 127) * 8] = __builtin_bit_cast(v8h, r0);
      *(v8h*)&Alds[(c1 >> 7) * ASTRIDE + DFEAT + (c1 & 127) * 8] = __builtin_bit_cast(v8h, r1);
      __syncthreads();
    }
  }
}

extern "C" void kernel_launch(void* const* d_in, const int* in_sizes, int n_in,
                              void* d_out, int out_size, void* d_ws, size_t ws_size,
                              hipStream_t stream) {
  const float* features = (const float*)d_in[0];
  const float* tsamp    = (const float*)d_in[1];
  const float* Wx       = (const float*)d_in[2];
  const float* Wh       = (const float*)d_in[3];
  const float* bias     = (const float*)d_in[4];
  const float* wtau     = (const float*)d_in[5];
  const float* h0       = (const float*)d_in[6];
  float* out = (float*)d_out;

  const size_t need = 4096 + (size_t)PKT_BYTES;
  if (ws_size >= need) {
    unsigned* pkt = (unsigned*)((char*)d_ws + 4096);
    hipMemsetAsync(d_ws, 0, need, stream);           // zero packet tags
    hipLaunchKernelGGL(ltc_rnn_kernel, dim3(256), dim3(1024), 0, stream,
                       features, tsamp, Wx, Wh, bias, wtau, h0, out, pkt);
  } else {
    unsigned*  flags = (unsigned*)d_ws;
    _Float16*  hbufs = (_Float16*)((char*)d_ws + 4096);
    hipMemsetAsync(d_ws, 0, 4096, stream);
    hipLaunchKernelGGL(ltc_rnn_fallback, dim3(256), dim3(1024), 0, stream,
                       features, tsamp, Wx, Wh, bias, wtau, h0, out, flags, hbufs);
  }
}

// Round 6
// 1241.955 us; speedup vs baseline: 1.1043x; 1.1043x over previous
//
#include <hip/hip_runtime.h>

typedef _Float16 v8h  __attribute__((ext_vector_type(8)));
typedef _Float16 v4h  __attribute__((ext_vector_type(4)));
typedef float    v4f  __attribute__((ext_vector_type(4)));
typedef unsigned int u32x4 __attribute__((ext_vector_type(4)));

#define BATCH   128
#define TSTEPS  256
#define DFEAT   256
#define UDIM    1024
#define NCOL    2048
#define ASTRIDE 1288   // LDS A stride (halfs)

// 256 blocks x 1024 threads. g = blockIdx%8 (row group of 16 batch rows),
// cb = blockIdx/8 (32 col-blocks). Wave w: cg=w&3 (16-col tile), ks=w>>2 (K-slice 320).
// Inter-block exchange: h tile via sc0/sc1 (IC-coherent) + per-block tagged flags —
// protocol byte-identical to the proven 915us kernel.
// Scheduling (this round):
//   - wave 4 = dedicated publisher: spins on LDS counter hsc (released by EW waves
//     the moment Hout is written), then pack -> store -> vmcnt -> flag. No S2 barrier.
//   - wave 15 = dedicated poller: staggered double-poll of the 32-flag line (two
//     outstanding loads checked alternately with vmcnt(1) -> half the discovery
//     period, 1/16th the poll traffic). Releases LDS counter hrdy; all other waves
//     spin on LDS (no IC traffic), then every thread stages its 2 h-chunks. S4 orders
//     staging vs next MFMA.
//   - out stores -> EW waves; x(t+1) prefetch -> waves 0-14 (+ wave4 takes row 15
//     post-publish); dt prefetch -> wave 14. Poller/publisher keep clean vmcnt streams.

__global__ __launch_bounds__(1024)
void ltc_rnn_kernel(const float* __restrict__ features,  // [128,256,256]
                    const float* __restrict__ tsteps,    // [128,256]
                    const float* __restrict__ Wx,        // [256,2048]
                    const float* __restrict__ Wh,        // [1024,2048]
                    const float* __restrict__ bias,      // [2048]
                    const float* __restrict__ wtau,      // [1024]
                    const float* __restrict__ h0,        // [128,1024]
                    float* __restrict__ out,             // [128,256,1024]
                    unsigned* __restrict__ flags,        // [8][64] u32 (tagged t+1)
                    _Float16* __restrict__ hbufs)        // 2 x [128,1024] fp16
{
  __shared__ _Float16 Alds[16 * ASTRIDE];
  __shared__ float    Plds[16 * 64 * 4];
  __shared__ _Float16 Hout[16][32];
  __shared__ float    dtlds[2][16];
  __shared__ unsigned hsc;    // EW -> publisher release (monotonic, 4 per step)
  __shared__ unsigned hrdy;   // poller -> all release (monotonic, value t+1)

  const int tid  = threadIdx.x;
  const int w    = tid >> 6;
  const int lane = tid & 63;
  const int n    = lane & 15;
  const int q    = lane >> 4;
  const int cg   = w & 3;
  const int ks   = w >> 2;
  const int g    = blockIdx.x & 7;
  const int cb   = blockIdx.x >> 3;
  const int u0   = cb * 32;

  if (tid == 0) { hsc = 0u; hrdy = 0u; }

  // ---- wave-stationary weights: fp32 -> fp16 VGPRs, once ----
  const int gcol = (n < 8) ? (u0 + cg * 8 + n) : (UDIM + u0 + cg * 8 + (n - 8));
  v8h bfr[10];
  #pragma unroll
  for (int c = 0; c < 10; ++c) {
    #pragma unroll
    for (int j = 0; j < 8; ++j) {
      const int k = ks * 320 + c * 32 + q * 8 + j;
      const float wv = (k < DFEAT) ? Wx[(size_t)k * NCOL + gcol]
                                   : Wh[(size_t)(k - DFEAT) * NCOL + gcol];
      bfr[c][j] = (_Float16)wv;
    }
  }

  const float bias_own = bias[gcol];
  const int   u_lane   = u0 + cg * 8 + (n & 7);
  const float tau      = logf(1.0f + __expf(wtau[u_lane]));

  float h_reg[4];
  #pragma unroll
  for (int i = 0; i < 4; ++i)
    h_reg[i] = h0[(size_t)(g * 16 + q * 4 + i) * UDIM + u_lane];

  // ---- pre-loop staging: x(0), dt(0), h0 ----
  if (tid < 16) dtlds[0][tid] = tsteps[(size_t)(g * 16 + tid) * TSTEPS + 0];
  {
    const int r = tid >> 6, k4 = tid & 63;
    v4f x4 = *(const v4f*)(features + (size_t)(g * 16 + r) * (TSTEPS * DFEAT) + k4 * 4);
    v4h xh = {(_Float16)x4.x, (_Float16)x4.y, (_Float16)x4.z, (_Float16)x4.w};
    *(v4h*)&Alds[r * ASTRIDE + k4 * 4] = xh;
    #pragma unroll
    for (int jj = 0; jj < 4; ++jj) {
      const int c = tid + jj * 1024, hr = c >> 8, hk4 = c & 255;
      v4f h4 = *(const v4f*)(h0 + (size_t)(g * 16 + hr) * UDIM + hk4 * 4);
      v4h hh = {(_Float16)h4.x, (_Float16)h4.y, (_Float16)h4.z, (_Float16)h4.w};
      *(v4h*)&Alds[hr * ASTRIDE + DFEAT + hk4 * 4] = hh;
    }
  }
  __syncthreads();

  for (int t = 0; t < TSTEPS; ++t) {
    const bool more = (t + 1 < TSTEPS);
    _Float16* hdst = hbufs + ((t + 1) & 1) * (BATCH * UDIM);

    // ---- MFMA: 16 rows x 16 cols x K-slice 320, dual accumulator chains ----
    {
      v4f acc0 = {0.f, 0.f, 0.f, 0.f};
      v4f acc1 = {0.f, 0.f, 0.f, 0.f};
      const _Float16* abase = &Alds[n * ASTRIDE + ks * 320 + q * 8];
      #pragma unroll
      for (int c = 0; c < 10; c += 2) {
        v8h a0 = *(const v8h*)(abase + c * 32);
        v8h a1 = *(const v8h*)(abase + (c + 1) * 32);
        acc0 = __builtin_amdgcn_mfma_f32_16x16x32_f16(a0, bfr[c],     acc0, 0, 0, 0);
        acc1 = __builtin_amdgcn_mfma_f32_16x16x32_f16(a1, bfr[c + 1], acc1, 0, 0, 0);
      }
      v4f acc = acc0 + acc1;
      *(v4f*)&Plds[(w * 64 + lane) * 4] = acc;
    }
    __syncthreads();                                   // S1: Plds ready

    // ======================= per-wave roles after S1 =======================
    if (w < 4) {
      // ---- EW waves: reduce + elementwise; Hout -> LDS; release hsc; out; x row w
      v4f p = *(v4f*)&Plds[((0 * 4 + w) * 64 + lane) * 4];
      #pragma unroll
      for (int s = 1; s < 4; ++s) {
        v4f ps = *(v4f*)&Plds[((s * 4 + w) * 64 + lane) * 4];
        p.x += ps.x; p.y += ps.y; p.z += ps.z; p.w += ps.w;
      }
      float pf[4], pa[4];
      #pragma unroll
      for (int i = 0; i < 4; ++i) {
        const float v = p[i] + bias_own;
        const float o = __shfl_xor(v, 8);
        pf[i] = v; pa[i] = o;
      }
      float outv[4];
      if (n < 8) {
        #pragma unroll
        for (int i = 0; i < 4; ++i) {
          const int   row_l = q * 4 + i;
          const float dt    = dtlds[t & 1][row_l];
          const float f     = 1.0f / (1.0f + __expf(-pf[i]));
          const float av    = 2.0f / (1.0f + __expf(-2.0f * pa[i])) - 1.0f;
          const float decay = __expf(-dt * (tau + f));
          const float hn    = (h_reg[i] - av) * decay + av;
          h_reg[i] = hn;
          outv[i]  = hn;
          Hout[row_l][w * 8 + n] = (_Float16)hn;
        }
      }
      if (lane == 0)
        __hip_atomic_fetch_add(&hsc, 1u, __ATOMIC_RELEASE, __HIP_MEMORY_SCOPE_WORKGROUP);
      // out stores (fire and forget)
      if (n < 8) {
        #pragma unroll
        for (int i = 0; i < 4; ++i) {
          const int row = g * 16 + q * 4 + i;
          out[(size_t)row * (TSTEPS * UDIM) + (size_t)t * UDIM + u_lane] = outv[i];
        }
      }
      // x(t+1) prefetch, row w
      if (more) {
        v4f x4 = *(const v4f*)(features + (size_t)(g * 16 + w) * (TSTEPS * DFEAT)
                               + (size_t)(t + 1) * DFEAT + lane * 4);
        v4h xh = {(_Float16)x4.x, (_Float16)x4.y, (_Float16)x4.z, (_Float16)x4.w};
        *(v4h*)&Alds[w * ASTRIDE + lane * 4] = xh;
      }
    } else if (w == 4) {
      // ---- publisher: wait EW, pack Hout -> store -> ack -> flag; then x rows 4,15
      if (more) {
        const unsigned target = 4u * (unsigned)(t + 1);
        while (__hip_atomic_load(&hsc, __ATOMIC_ACQUIRE, __HIP_MEMORY_SCOPE_WORKGROUP) < target) {}
        const int row = lane >> 2, c8 = lane & 3;
        v8h hv = *(v8h*)&Hout[row][c8 * 8];
        _Float16* dp = hdst + (size_t)(g * 16 + row) * UDIM + u0 + c8 * 8;
        asm volatile("global_store_dwordx4 %0, %1, off sc0 sc1\n\t"
                     "s_waitcnt vmcnt(0)"
                     :: "v"(dp), "v"(__builtin_bit_cast(u32x4, hv)) : "memory");
        if (lane == 0) {
          unsigned tgv = (unsigned)(t + 1);
          asm volatile("global_store_dword %0, %1, off sc0 sc1"
                       :: "v"(&flags[g * 64 + cb]), "v"(tgv) : "memory");
        }
        #pragma unroll
        for (int rr = 0; rr < 2; ++rr) {
          const int row2 = rr ? 15 : 4;
          v4f x4 = *(const v4f*)(features + (size_t)(g * 16 + row2) * (TSTEPS * DFEAT)
                                 + (size_t)(t + 1) * DFEAT + lane * 4);
          v4h xh = {(_Float16)x4.x, (_Float16)x4.y, (_Float16)x4.z, (_Float16)x4.w};
          *(v4h*)&Alds[row2 * ASTRIDE + lane * 4] = xh;
        }
      }
    } else if (w == 15) {
      // ---- poller: staggered double-poll on the 32-flag line; release hrdy
      if (more) {
        const unsigned* fp = &flags[g * 64 + (lane & 31)];
        const unsigned  tg = (unsigned)t;      // stale if flag <= t
        unsigned va, vb;
        asm volatile("global_load_dword %0, %1, off sc0 sc1"
                     : "=v"(va) : "v"(fp) : "memory");
        for (;;) {
          asm volatile("global_load_dword %0, %1, off sc0 sc1"
                       : "=v"(vb) : "v"(fp) : "memory");
          asm volatile("s_waitcnt vmcnt(1)" : "+v"(va) :: "memory");
          if (__ballot(va <= tg) == 0ull) break;
          asm volatile("global_load_dword %0, %1, off sc0 sc1"
                       : "=v"(va) : "v"(fp) : "memory");
          asm volatile("s_waitcnt vmcnt(1)" : "+v"(vb) :: "memory");
          if (__ballot(vb <= tg) == 0ull) break;
        }
        asm volatile("s_waitcnt vmcnt(0)" ::: "memory");   // drain dangling poll
        if (lane == 0)
          __hip_atomic_store(&hrdy, (unsigned)(t + 1), __ATOMIC_RELEASE,
                             __HIP_MEMORY_SCOPE_WORKGROUP);
      }
    } else {
      // ---- waves 5..14: x(t+1) prefetch row w; wave14 also dt(t+1)
      if (more) {
        if (w == 14 && lane < 16)
          dtlds[(t + 1) & 1][lane] = tsteps[(size_t)(g * 16 + lane) * TSTEPS + t + 1];
        v4f x4 = *(const v4f*)(features + (size_t)(g * 16 + w) * (TSTEPS * DFEAT)
                               + (size_t)(t + 1) * DFEAT + lane * 4);
        v4h xh = {(_Float16)x4.x, (_Float16)x4.y, (_Float16)x4.z, (_Float16)x4.w};
        *(v4h*)&Alds[w * ASTRIDE + lane * 4] = xh;
      }
    }

    // ---- all waves: LDS wait for discovery, then stage h(t+1), then S4 ----
    if (more) {
      while (__hip_atomic_load(&hrdy, __ATOMIC_ACQUIRE, __HIP_MEMORY_SCOPE_WORKGROUP)
             < (unsigned)(t + 1)) {}
      const _Float16* hsrc = hbufs + ((t + 1) & 1) * (BATCH * UDIM);
      const int c0 = tid, c1 = tid + 1024;
      const _Float16* p0 = hsrc + (size_t)(g * 16 + (c0 >> 7)) * UDIM + (c0 & 127) * 8;
      const _Float16* p1 = hsrc + (size_t)(g * 16 + (c1 >> 7)) * UDIM + (c1 & 127) * 8;
      u32x4 r0, r1;
      asm volatile("global_load_dwordx4 %0, %2, off sc0 sc1\n\t"
                   "global_load_dwordx4 %1, %3, off sc0 sc1\n\t"
                   "s_waitcnt vmcnt(0)"
                   : "=v"(r0), "=v"(r1) : "v"(p0), "v"(p1) : "memory");
      *(v8h*)&Alds[(c0 >> 7) * ASTRIDE + DFEAT + (c0 & 127) * 8] = __builtin_bit_cast(v8h, r0);
      *(v8h*)&Alds[(c1 >> 7) * ASTRIDE + DFEAT + (c1 & 127) * 8] = __builtin_bit_cast(v8h, r1);
      __syncthreads();                                 // S4: A(t+1) ready
    }
  }
}

extern "C" void kernel_launch(void* const* d_in, const int* in_sizes, int n_in,
                              void* d_out, int out_size, void* d_ws, size_t ws_size,
                              hipStream_t stream) {
  const float* features = (const float*)d_in[0];
  const float* tsamp    = (const float*)d_in[1];
  const float* Wx       = (const float*)d_in[2];
  const float* Wh       = (const float*)d_in[3];
  const float* bias     = (const float*)d_in[4];
  const float* wtau     = (const float*)d_in[5];
  const float* h0       = (const float*)d_in[6];
  float*     out    = (float*)d_out;
  unsigned*  flags  = (unsigned*)d_ws;
  _Float16*  hbufs  = (_Float16*)((char*)d_ws + 4096);

  hipMemsetAsync(d_ws, 0, 4096, stream);   // zero flags (ws is poisoned)
  hipLaunchKernelGGL(ltc_rnn_kernel, dim3(256), dim3(1024), 0, stream,
                     features, tsamp, Wx, Wh, bias, wtau, h0, out, flags, hbufs);
}

// Round 7
// 998.439 us; speedup vs baseline: 1.3736x; 1.2439x over previous
//
#include <hip/hip_runtime.h>

typedef _Float16 v8h  __attribute__((ext_vector_type(8)));
typedef _Float16 v4h  __attribute__((ext_vector_type(4)));
typedef float    v4f  __attribute__((ext_vector_type(4)));
typedef unsigned int u32x4 __attribute__((ext_vector_type(4)));

#define BATCH   128
#define TSTEPS  256
#define DFEAT   256
#define UDIM    1024
#define NCOL    2048
#define ASTRIDE 1288   // LDS A stride (halfs)

// 256 blocks x 1024 threads. g = blockIdx%8 (row group of 16 batch rows),
// cb = blockIdx/8 (32 col-blocks of 32 u-cols = 64 pre-cols).
// MFMA partition (this round): wave w -> ks = w>>1 (8 K-slices of 160),
// cg = w&1; each wave computes TWO 16-pre-col tiles (cg*2, cg*2+1) sharing ONE
// A-fragment read -> A-LDS-read traffic halved vs 4ks x 4cg (164->82 KB/step).
// Reduce depth 8 (Plds 32 KB). EW waves 0..3 own tile w (same col semantics
// as proven kernel). Exchange protocol byte-identical to the proven 915us
// kernel: sc0+sc1 h-store -> vmcnt ack -> tagged flag; early probe; all-wave
// poll (vmcnt-sleep, no LDS spinning); per-thread h staging; S4 barrier.

__global__ __launch_bounds__(1024)
void ltc_rnn_kernel(const float* __restrict__ features,  // [128,256,256]
                    const float* __restrict__ tsteps,    // [128,256]
                    const float* __restrict__ Wx,        // [256,2048]
                    const float* __restrict__ Wh,        // [1024,2048]
                    const float* __restrict__ bias,      // [2048]
                    const float* __restrict__ wtau,      // [1024]
                    const float* __restrict__ h0,        // [128,1024]
                    float* __restrict__ out,             // [128,256,1024]
                    unsigned* __restrict__ flags,        // [8][64] u32 (tagged t+1)
                    _Float16* __restrict__ hbufs)        // 2 x [128,1024] fp16
{
  __shared__ _Float16 Alds[16 * ASTRIDE];
  __shared__ float    Plds[8 * 4 * 64 * 4];   // [ks][tile][lane][4] = 32 KB
  __shared__ _Float16 Hout[16][40];           // padded: 16B-aligned rows, bank-spread
  __shared__ float    dtlds[2][16];

  const int tid  = threadIdx.x;
  const int w    = tid >> 6;
  const int lane = tid & 63;
  const int n    = lane & 15;
  const int q    = lane >> 4;
  const int cg   = w & 1;        // col-pair group: tiles cg*2, cg*2+1
  const int ks   = w >> 1;       // K-slice 0..7 (160 each)
  const int we   = w & 3;        // EW tile for waves 0..3
  const int g    = blockIdx.x & 7;
  const int cb   = blockIdx.x >> 3;
  const int u0   = cb * 32;

  // ---- wave-stationary weights: fp32 -> fp16 VGPRs, once (2 tiles x 5 ksteps) ----
  v8h bfr[2][5];
  #pragma unroll
  for (int tt = 0; tt < 2; ++tt) {
    const int tile = cg * 2 + tt;
    const int gcolw = (n < 8) ? (u0 + tile * 8 + n) : (UDIM + u0 + tile * 8 + (n - 8));
    #pragma unroll
    for (int c = 0; c < 5; ++c) {
      #pragma unroll
      for (int j = 0; j < 8; ++j) {
        const int k = ks * 160 + c * 32 + q * 8 + j;
        const float wv = (k < DFEAT) ? Wx[(size_t)k * NCOL + gcolw]
                                     : Wh[(size_t)(k - DFEAT) * NCOL + gcolw];
        bfr[tt][c][j] = (_Float16)wv;
      }
    }
  }

  // EW-only per-thread values (used by waves 0..3; 'we' keeps indices in-bounds)
  const int   gcolE   = (n < 8) ? (u0 + we * 8 + n) : (UDIM + u0 + we * 8 + (n - 8));
  const float bias_own = bias[gcolE];
  const int   u_lane   = u0 + we * 8 + (n & 7);
  const float tau      = logf(1.0f + __expf(wtau[u_lane]));

  float h_reg[4];
  #pragma unroll
  for (int i = 0; i < 4; ++i)
    h_reg[i] = h0[(size_t)(g * 16 + q * 4 + i) * UDIM + u_lane];

  // ---- pre-loop staging: x(0), dt(0), h0 ----
  if (tid < 16) dtlds[0][tid] = tsteps[(size_t)(g * 16 + tid) * TSTEPS + 0];
  {
    const int r = tid >> 6, k4 = tid & 63;
    v4f x4 = *(const v4f*)(features + (size_t)(g * 16 + r) * (TSTEPS * DFEAT) + k4 * 4);
    v4h xh = {(_Float16)x4.x, (_Float16)x4.y, (_Float16)x4.z, (_Float16)x4.w};
    *(v4h*)&Alds[r * ASTRIDE + k4 * 4] = xh;
    #pragma unroll
    for (int jj = 0; jj < 4; ++jj) {
      const int c = tid + jj * 1024, hr = c >> 8, hk4 = c & 255;
      v4f h4 = *(const v4f*)(h0 + (size_t)(g * 16 + hr) * UDIM + hk4 * 4);
      v4h hh = {(_Float16)h4.x, (_Float16)h4.y, (_Float16)h4.z, (_Float16)h4.w};
      *(v4h*)&Alds[hr * ASTRIDE + DFEAT + hk4 * 4] = hh;
    }
  }
  __syncthreads();

  for (int t = 0; t < TSTEPS; ++t) {
    const bool more = (t + 1 < TSTEPS);
    _Float16* hdst = hbufs + ((t + 1) & 1) * (BATCH * UDIM);

    // ---- MFMA: one A-fragment feeds two col-tiles (dual independent chains) ----
    {
      v4f acc0 = {0.f, 0.f, 0.f, 0.f};
      v4f acc1 = {0.f, 0.f, 0.f, 0.f};
      const _Float16* abase = &Alds[n * ASTRIDE + ks * 160 + q * 8];
      #pragma unroll
      for (int c = 0; c < 5; ++c) {
        v8h a = *(const v8h*)(abase + c * 32);
        acc0 = __builtin_amdgcn_mfma_f32_16x16x32_f16(a, bfr[0][c], acc0, 0, 0, 0);
        acc1 = __builtin_amdgcn_mfma_f32_16x16x32_f16(a, bfr[1][c], acc1, 0, 0, 0);
      }
      *(v4f*)&Plds[((ks * 4 + cg * 2 + 0) * 64 + lane) * 4] = acc0;
      *(v4f*)&Plds[((ks * 4 + cg * 2 + 1) * 64 + lane) * 4] = acc1;
    }
    __syncthreads();                                   // S1: Plds ready

    // ---- reduce (8 partials) + elementwise (waves 0..3, tile we=w) ----
    float outv[4];
    if (w < 4) {
      v4f p = *(v4f*)&Plds[((0 * 4 + w) * 64 + lane) * 4];
      #pragma unroll
      for (int s = 1; s < 8; ++s) {
        v4f ps = *(v4f*)&Plds[((s * 4 + w) * 64 + lane) * 4];
        p.x += ps.x; p.y += ps.y; p.z += ps.z; p.w += ps.w;
      }
      float pf[4], pa[4];
      #pragma unroll
      for (int i = 0; i < 4; ++i) {
        const float v = p[i] + bias_own;
        const float o = __shfl_xor(v, 8);
        pf[i] = v; pa[i] = o;
      }
      if (n < 8) {
        #pragma unroll
        for (int i = 0; i < 4; ++i) {
          const int   row_l = q * 4 + i;
          const float dt    = dtlds[t & 1][row_l];
          const float f     = 1.0f / (1.0f + __expf(-pf[i]));
          const float av    = 2.0f / (1.0f + __expf(-2.0f * pa[i])) - 1.0f;
          const float decay = __expf(-dt * (tau + f));
          const float hn    = (h_reg[i] - av) * decay + av;
          h_reg[i] = hn;
          outv[i]  = hn;
          Hout[row_l][w * 8 + n] = (_Float16)hn;
        }
      }
    }
    __syncthreads();                                   // S2: Hout ready

    // ---- wave0: packed h-store to IC, ack, publish tagged flag ----
    if (w == 0 && more) {
      const int row = lane >> 2, c8 = lane & 3;
      v8h hv = *(v8h*)&Hout[row][c8 * 8];
      _Float16* dp = hdst + (size_t)(g * 16 + row) * UDIM + u0 + c8 * 8;
      asm volatile("global_store_dwordx4 %0, %1, off sc0 sc1\n\t"
                   "s_waitcnt vmcnt(0)"
                   :: "v"(dp), "v"(__builtin_bit_cast(u32x4, hv)) : "memory");
      if (lane == 0) {
        unsigned tg = (unsigned)(t + 1);
        asm volatile("global_store_dword %0, %1, off sc0 sc1"
                     :: "v"(&flags[g * 64 + cb]), "v"(tg) : "memory");
      }
    }

    // ---- early flag probe (non-blocking), then off-critical-path work ----
    const unsigned* fp = &flags[g * 64 + (lane & 31)];
    unsigned v0 = 0;
    if (more) {
      asm volatile("global_load_dword %0, %1, off sc0 sc1"
                   : "=v"(v0) : "v"(fp) : "memory");
    }

    if (w < 4 && n < 8) {
      #pragma unroll
      for (int i = 0; i < 4; ++i) {
        const int row = g * 16 + q * 4 + i;
        out[(size_t)row * (TSTEPS * UDIM) + (size_t)t * UDIM + u_lane] = outv[i];
      }
    }
    if (more) {
      if (tid < 16) dtlds[(t + 1) & 1][tid] = tsteps[(size_t)(g * 16 + tid) * TSTEPS + t + 1];
      const int r = tid >> 6, k4 = tid & 63;
      v4f x4 = *(const v4f*)(features + (size_t)(g * 16 + r) * (TSTEPS * DFEAT)
                             + (size_t)(t + 1) * DFEAT + k4 * 4);
      v4h xh = {(_Float16)x4.x, (_Float16)x4.y, (_Float16)x4.z, (_Float16)x4.w};
      *(v4h*)&Alds[r * ASTRIDE + k4 * 4] = xh;
    }

    // ---- all waves: check probe, spin (vmcnt-sleep) only if stale; stage h(t+1) ----
    if (more) {
      const unsigned tg = (unsigned)t;                 // stale if flag <= t
      asm volatile("s_waitcnt vmcnt(0)" : "+v"(v0) :: "memory");  // reg-tied drain
      if (__ballot(v0 <= tg) != 0ull) {
        for (;;) {
          unsigned v;
          asm volatile("global_load_dword %0, %1, off sc0 sc1\n\t"
                       "s_waitcnt vmcnt(0)"
                       : "=v"(v) : "v"(fp) : "memory");
          if (__ballot(v <= tg) == 0ull) break;
        }
      }
      // per-thread h staging (no barrier between poll and load)
      const _Float16* hsrc = hbufs + ((t + 1) & 1) * (BATCH * UDIM);
      const int c0 = tid, c1 = tid + 1024;
      const _Float16* p0 = hsrc + (size_t)(g * 16 + (c0 >> 7)) * UDIM + (c0 & 127) * 8;
      const _Float16* p1 = hsrc + (size_t)(g * 16 + (c1 >> 7)) * UDIM + (c1 & 127) * 8;
      u32x4 r0, r1;
      asm volatile("global_load_dwordx4 %0, %2, off sc0 sc1\n\t"
                   "global_load_dwordx4 %1, %3, off sc0 sc1\n\t"
                   "s_waitcnt vmcnt(0)"
                   : "=v"(r0), "=v"(r1) : "v"(p0), "v"(p1) : "memory");
      *(v8h*)&Alds[(c0 >> 7) * ASTRIDE + DFEAT + (c0 & 127) * 8] = __builtin_bit_cast(v8h, r0);
      *(v8h*)&Alds[(c1 >> 7) * ASTRIDE + DFEAT + (c1 & 127) * 8] = __builtin_bit_cast(v8h, r1);
      __syncthreads();                                 // S4: A(t+1) ready
    }
  }
}

extern "C" void kernel_launch(void* const* d_in, const int* in_sizes, int n_in,
                              void* d_out, int out_size, void* d_ws, size_t ws_size,
                              hipStream_t stream) {
  const float* features = (const float*)d_in[0];
  const float* tsamp    = (const float*)d_in[1];
  const float* Wx       = (const float*)d_in[2];
  const float* Wh       = (const float*)d_in[3];
  const float* bias     = (const float*)d_in[4];
  const float* wtau     = (const float*)d_in[5];
  const float* h0       = (const float*)d_in[6];
  float*     out    = (float*)d_out;
  unsigned*  flags  = (unsigned*)d_ws;
  _Float16*  hbufs  = (_Float16*)((char*)d_ws + 4096);

  hipMemsetAsync(d_ws, 0, 4096, stream);   // zero flags (ws is poisoned)
  hipLaunchKernelGGL(ltc_rnn_kernel, dim3(256), dim3(1024), 0, stream,
                     features, tsamp, Wx, Wh, bias, wtau, h0, out, flags, hbufs);
}